// Round 5
// baseline (332.670 us; speedup 1.0000x reference)
//
#include <hip/hip_runtime.h>

// SSN soft-superpixel assignment. Fixed shapes: x (4,32,256,256) fp32, s=16.
// M = 0 -> the two grid channels are identically zero everywhere (px and
// centroids), so they cancel in distances and updates; drop them (C=32).
//
// 3-kernel pipeline; the 254 MB of output zeros is split across all three
// kernels as barrier-free end-of-kernel stores (a __syncthreads would emit
// s_waitcnt vmcnt(0) and drain them — so they are issued only after the LAST
// barrier of each kernel, draining at s_endpgm under the next CU-round's
// compute). Values (9-neighborhood) are scattered directly from k_aff9's LDS.
// Zero strips: k_cent0 rows [0,21), k_part [21,43) (unconditional — later
// kernels' scatter overwrites, stream order), k_aff9 [43,64) (3x3-excluded,
// scatter is in the same kernel).
#define B_  4
#define C_  32
#define W_  256
#define N_  65536   // H*W
#define NH_ 16      // 16x16 superpixel grid
#define S_  256
#define PADP 260    // padded pixel stride for LDS [c][p] / [k][p] tiles
#define PSTR 304    // per-block partial stride: 288 num + 9 den + pad

__device__ __forceinline__ float wave_sum(float v) {
    v += __shfl_down(v, 32);
    v += __shfl_down(v, 16);
    v += __shfl_down(v, 8);
    v += __shfl_down(v, 4);
    v += __shfl_down(v, 2);
    v += __shfl_down(v, 1);
    return v;  // lane 0 holds the 64-lane sum
}

// Stage this block's 16x16x32 tile of x into xsh[c][p] (p = py*16+px),
// coalesced float4: idx -> channel c = idx>>6, f4 p4 = idx&63.
__device__ __forceinline__ void stage_tile(const float* __restrict__ x,
                                           int b, int sy, int sx, int t,
                                           float (*xsh)[PADP]) {
    const float* base = x + (size_t)b * C_ * N_ + (sy * 16) * W_ + sx * 16;
    #pragma unroll
    for (int i = 0; i < 8; ++i) {
        const int idx = i * 256 + t;
        const int c = idx >> 6, p4 = idx & 63;
        const float4 v = *(const float4*)(base + (size_t)c * N_ + (p4 >> 2) * W_ + (p4 & 3) * 4);
        *(float4*)&xsh[c][p4 * 4] = v;
    }
}

// Per-pixel softmax over the 3x3 superpixel neighborhood (cl[k] zeroed for
// invalid k; masked to aff=0 anyway). Equivalent to ref softmax(-dist)+mask.
__device__ __forceinline__ void compute_aff(const float xv[C_], const float (*cl)[C_],
                                            int sy, int sx, float aff[9]) {
    float dist[9];
    #pragma unroll
    for (int k = 0; k < 9; ++k) {
        const int ny = sy + k / 3 - 1, nx = sx + k % 3 - 1;
        const bool valid = (ny >= 0) & (ny < NH_) & (nx >= 0) & (nx < NH_);
        float d = 0.f;
        #pragma unroll
        for (int c4 = 0; c4 < C_ / 4; ++c4) {
            const float4 cv = *(const float4*)&cl[k][c4 * 4];   // LDS broadcast
            const float d0 = xv[c4 * 4 + 0] - cv.x;
            const float d1 = xv[c4 * 4 + 1] - cv.y;
            const float d2 = xv[c4 * 4 + 2] - cv.z;
            const float d3 = xv[c4 * 4 + 3] - cv.w;
            d += d0 * d0 + d1 * d1 + d2 * d2 + d3 * d3;
        }
        dist[k] = valid ? d : 1e30f;
    }
    float mind = dist[0];
    #pragma unroll
    for (int k = 1; k < 9; ++k) mind = fminf(mind, dist[k]);
    float sum = 0.f;
    #pragma unroll
    for (int k = 0; k < 9; ++k) {
        const float e = (dist[k] < 1e29f) ? __expf(mind - dist[k]) : 0.f;
        aff[k] = e;
        sum += e;
    }
    const float inv = 1.f / sum;   // home superpixel always valid
    #pragma unroll
    for (int k = 0; k < 9; ++k) aff[k] *= inv;
}

// K1: initial centroids (tile means) + zero strip rows [0,21). No barriers:
// loads issue first, strip stores second (vmcnt retires in order, so load
// waits don't drain them), shuffle-reduce chains hide the store drain.
__global__ __launch_bounds__(256) void k_cent0(const float* __restrict__ x,
                                               float* __restrict__ cent0,
                                               float* __restrict__ out) {
    const int blk = blockIdx.x;            // b*S_ + s
    const int b = blk >> 8, s = blk & 255;
    const int sy = s >> 4, sx = s & 15;
    const int t = threadIdx.x;
    const int w = t >> 6, lane = t & 63;
    const float* base = x + (size_t)b * C_ * N_ + (sy * 16) * W_ + sx * 16;
    float psum[8];
    #pragma unroll
    for (int i = 0; i < 8; ++i) {          // loads first (independent)
        const int c = i * 4 + w;
        const float4 v = *(const float4*)(base + (size_t)c * N_ + (lane >> 2) * W_ + (lane & 3) * 4);
        psum[i] = v.x + v.y + v.z + v.w;
    }
    {   // zero strip rows [0,21), unconditional (k_aff9 scatter overwrites later)
        const float4 z = make_float4(0.f, 0.f, 0.f, 0.f);
        float4* plane = (float4*)out + ((size_t)blk << 14);
        #pragma unroll
        for (int i = 0; i < 21; ++i) plane[i * 256 + t] = z;
    }
    #pragma unroll
    for (int i = 0; i < 8; ++i) {          // shuffle chains overlap store drain
        const float sm = wave_sum(psum[i]);
        if (lane == 0) cent0[(size_t)blk * C_ + i * 4 + w] = sm * (1.0f / 256.0f);
    }
}

// K2: iteration 0 partials + zero strip rows [21,43) issued AFTER the last
// barrier (hidden under the phase-B LDS dots and the next CU round).
__global__ __launch_bounds__(256) void k_part(const float* __restrict__ x,
                                              const float* __restrict__ cent0,
                                              float* __restrict__ part,
                                              float* __restrict__ out) {
    const int blk = blockIdx.x;
    const int b = blk >> 8, s = blk & 255;
    const int sy = s >> 4, sx = s & 15;
    const int t = threadIdx.x;
    const int w = t >> 6, lane = t & 63;
    __shared__ float cl[9][C_];
    __shared__ float xsh[C_][PADP];
    __shared__ float affs[9][PADP];
    __shared__ float lden[4][9];
    {   // cl fill: k=0..7 by all, k=8 by t<32
        const int k = t >> 5, c = t & 31;
        const int ny = sy + k / 3 - 1, nx = sx + k % 3 - 1;
        const bool valid = (ny >= 0) & (ny < NH_) & (nx >= 0) & (nx < NH_);
        cl[k][c] = valid ? cent0[(size_t)(b * S_ + ny * NH_ + nx) * C_ + c] : 0.f;
    }
    if (t < 32) {
        const int ny = sy + 1, nx = sx + 1;
        const bool valid = (ny < NH_) & (nx < NH_);
        cl[8][t] = valid ? cent0[(size_t)(b * S_ + ny * NH_ + nx) * C_ + t] : 0.f;
    }
    stage_tile(x, b, sy, sx, t, xsh);
    __syncthreads();
    float xv[C_];
    #pragma unroll
    for (int c = 0; c < C_; ++c) xv[c] = xsh[c][t];   // conflict-free
    float aff[9];
    compute_aff(xv, cl, sy, sx, aff);
    #pragma unroll
    for (int k = 0; k < 9; ++k) {
        affs[k][t] = aff[k];
        const float v = wave_sum(aff[k]);
        if (lane == 0) lden[w][k] = v;
    }
    __syncthreads();                       // LAST barrier
    {   // zero strip rows [21,43): outstanding through phase B, drains at end
        const float4 z = make_float4(0.f, 0.f, 0.f, 0.f);
        float4* plane = (float4*)out + ((size_t)blk << 14);
        #pragma unroll
        for (int i = 21; i < 43; ++i) plane[i * 256 + t] = z;
    }
    {   // Phase B: outputs t = k*32+c for k=0..7; t<32 also k=8.
        const int k = t >> 5, c = t & 31;
        float acc = 0.f;
        #pragma unroll 4
        for (int p = 0; p < 256; p += 4) {
            const float4 a = *(const float4*)&affs[k][p];
            const float4 xc = *(const float4*)&xsh[c][p];
            acc += a.x * xc.x + a.y * xc.y + a.z * xc.z + a.w * xc.w;
        }
        part[(size_t)blk * PSTR + t] = acc;
    }
    if (t < 32) {
        float acc = 0.f;
        #pragma unroll 4
        for (int p = 0; p < 256; p += 4) {
            const float4 a = *(const float4*)&affs[8][p];
            const float4 xc = *(const float4*)&xsh[t][p];
            acc += a.x * xc.x + a.y * xc.y + a.z * xc.z + a.w * xc.w;
        }
        part[(size_t)blk * PSTR + 256 + t] = acc;
    }
    if (t < 9)
        part[(size_t)blk * PSTR + 288 + t] =
            lden[0][t] + lden[1][t] + lden[2][t] + lden[3][t];
}

// cent1[b,(ny,nx),c] = num/(den+1e-16), gathered from 9 source blocks'
// partials (part is L2-hot, 1.2 MB).
__device__ __forceinline__ float gather_cent1(const float* __restrict__ part,
                                              int b, int ny, int nx, int c) {
    float num = 0.f, den = 0.f;
    #pragma unroll
    for (int k2 = 0; k2 < 9; ++k2) {
        const int syp = ny - (k2 / 3 - 1), sxp = nx - (k2 % 3 - 1);
        if ((syp >= 0) & (syp < NH_) & (sxp >= 0) & (sxp < NH_)) {
            const size_t base = (size_t)(b * S_ + syp * NH_ + sxp) * PSTR;
            num += part[base + k2 * 32 + c];
            den += part[base + 288 + k2];
        }
    }
    return num / (den + 1e-16f);
}

// K3: iteration-1 affinities vs cent1 (gathered in-kernel); after the last
// barrier: conditional zero strip rows [43,64) + direct value scatter.
__global__ __launch_bounds__(256) void k_aff9(const float* __restrict__ x,
                                              const float* __restrict__ part,
                                              float* __restrict__ out) {
    const int blk = blockIdx.x;
    const int b = blk >> 8, s = blk & 255;
    const int sy = s >> 4, sx = s & 15;
    const int t = threadIdx.x;
    __shared__ float cl[9][C_];
    __shared__ float xsh[C_][PADP];
    __shared__ float affs[9][PADP];
    {   // cl = cent1 of the 9 neighbors, computed on the fly
        const int k = t >> 5, c = t & 31;
        const int ny = sy + k / 3 - 1, nx = sx + k % 3 - 1;
        const bool valid = (ny >= 0) & (ny < NH_) & (nx >= 0) & (nx < NH_);
        cl[k][c] = valid ? gather_cent1(part, b, ny, nx, c) : 0.f;
    }
    if (t < 32) {
        const int ny = sy + 1, nx = sx + 1;
        const bool valid = (ny < NH_) & (nx < NH_);
        cl[8][t] = valid ? gather_cent1(part, b, ny, nx, t) : 0.f;
    }
    stage_tile(x, b, sy, sx, t, xsh);
    __syncthreads();
    float xv[C_];
    #pragma unroll
    for (int c = 0; c < C_; ++c) xv[c] = xsh[c][t];
    float aff[9];
    compute_aff(xv, cl, sy, sx, aff);
    #pragma unroll
    for (int k = 0; k < 9; ++k) affs[k][t] = aff[k];
    __syncthreads();                       // LAST barrier
    {   // zero strip rows [43,64), excluding the 3x3 neighborhood (scatter
        // targets in this kernel — cross-block, no ordering guarantee).
        const float4 z = make_float4(0.f, 0.f, 0.f, 0.f);
        float4* plane = (float4*)out + ((size_t)blk << 14);
        #pragma unroll
        for (int i = 43; i < 64; ++i) {
            const int q = i * 256 + t;
            const int ty = q >> 10;
            const int tx = (q >> 2) & 15;
            if (((unsigned)(ty - sy + 1) > 2u) | ((unsigned)(tx - sx + 1) > 2u))
                plane[q] = z;
        }
    }
    // Scatter: for valid neighbor k, write this tile's 16x16 values into
    // plane s'=(ny,nx) — 576 float4 total (64B row-segments).
    #pragma unroll
    for (int i = 0; i < 3; ++i) {
        const int idx = i * 256 + t;
        if (idx < 576) {
            const int k = idx >> 6, j4 = idx & 63;
            const int ny = sy + k / 3 - 1, nx = sx + k % 3 - 1;
            if ((ny >= 0) & (ny < NH_) & (nx >= 0) & (nx < NH_)) {
                const float4 v = *(const float4*)&affs[k][j4 * 4];
                const int gq = (sy * 16 + (j4 >> 2)) * 64 + sx * 4 + (j4 & 3);
                ((float4*)out)[((size_t)(b * S_ + ny * NH_ + nx) << 14) + gq] = v;
            }
        }
    }
    if ((blk | t) == 0) out[(size_t)B_ * S_ * N_] = 256.0f;  // output 1: S
}

extern "C" void kernel_launch(void* const* d_in, const int* in_sizes, int n_in,
                              void* d_out, int out_size, void* d_ws, size_t ws_size,
                              hipStream_t stream) {
    const float* x = (const float*)d_in[0];
    float* ws = (float*)d_ws;
    // ws layout (floats): cent0[32768] | part[1024*304]
    float* cent0 = ws;
    float* part  = ws + 32768;
    float* out   = (float*)d_out;

    hipLaunchKernelGGL(k_cent0, dim3(B_ * S_), dim3(256), 0, stream, x, cent0, out);
    hipLaunchKernelGGL(k_part,  dim3(B_ * S_), dim3(256), 0, stream, x, cent0, part, out);
    hipLaunchKernelGGL(k_aff9,  dim3(B_ * S_), dim3(256), 0, stream, x, part, out);
}

// Round 7
// 317.382 us; speedup vs baseline: 1.0482x; 1.0482x over previous
//
#include <hip/hip_runtime.h>

// SSN soft-superpixel assignment. Fixed shapes: x (4,32,256,256) fp32, s=16.
// M = 0 -> the two grid channels are identically zero everywhere (px and
// centroids), so they cancel in distances and updates; drop them (C=32).
//
// 3-kernel pipeline. 254 MB of output zeros is fused into k_part/k_aff9 as
// nontemporal stores with PARITY STAGGER: even blocks issue their strip
// before the first barrier (front-loads HBM; drain overlaps odd blocks'
// compute), odd blocks issue after the last barrier (drain overlaps even
// blocks' tails). k_part's strip is unconditional (k_aff9's scatter
// overwrites later in stream order); k_aff9's excludes its own 3x3 targets.
#define B_  4
#define C_  32
#define W_  256
#define N_  65536   // H*W
#define NH_ 16      // 16x16 superpixel grid
#define S_  256
#define PADP 260    // padded pixel stride for LDS [c][p] / [k][p] tiles
#define PSTR 304    // per-block partial stride: 288 num + 9 den + pad

typedef float vf4 __attribute__((ext_vector_type(4)));  // native vec for NT builtin

__device__ __forceinline__ float wave_sum(float v) {
    v += __shfl_down(v, 32);
    v += __shfl_down(v, 16);
    v += __shfl_down(v, 8);
    v += __shfl_down(v, 4);
    v += __shfl_down(v, 2);
    v += __shfl_down(v, 1);
    return v;  // lane 0 holds the 64-lane sum
}

__device__ __forceinline__ void nt_store4(float* p, float a, float b, float c, float d) {
    vf4 v = {a, b, c, d};
    __builtin_nontemporal_store(v, (vf4*)p);
}
__device__ __forceinline__ void nt_zero4(float* p) { nt_store4(p, 0.f, 0.f, 0.f, 0.f); }

// Stage this block's 16x16x32 tile of x into xsh[c][p] (p = py*16+px),
// coalesced float4: idx -> channel c = idx>>6, f4 p4 = idx&63.
__device__ __forceinline__ void stage_tile(const float* __restrict__ x,
                                           int b, int sy, int sx, int t,
                                           float (*xsh)[PADP]) {
    const float* base = x + (size_t)b * C_ * N_ + (sy * 16) * W_ + sx * 16;
    #pragma unroll
    for (int i = 0; i < 8; ++i) {
        const int idx = i * 256 + t;
        const int c = idx >> 6, p4 = idx & 63;
        const float4 v = *(const float4*)(base + (size_t)c * N_ + (p4 >> 2) * W_ + (p4 & 3) * 4);
        *(float4*)&xsh[c][p4 * 4] = v;
    }
}

// Per-pixel softmax over the 3x3 superpixel neighborhood (cl[k] zeroed for
// invalid k; masked to aff=0 anyway). Equivalent to ref softmax(-dist)+mask.
__device__ __forceinline__ void compute_aff(const float xv[C_], const float (*cl)[C_],
                                            int sy, int sx, float aff[9]) {
    float dist[9];
    #pragma unroll
    for (int k = 0; k < 9; ++k) {
        const int ny = sy + k / 3 - 1, nx = sx + k % 3 - 1;
        const bool valid = (ny >= 0) & (ny < NH_) & (nx >= 0) & (nx < NH_);
        float d = 0.f;
        #pragma unroll
        for (int c4 = 0; c4 < C_ / 4; ++c4) {
            const float4 cv = *(const float4*)&cl[k][c4 * 4];   // LDS broadcast
            const float d0 = xv[c4 * 4 + 0] - cv.x;
            const float d1 = xv[c4 * 4 + 1] - cv.y;
            const float d2 = xv[c4 * 4 + 2] - cv.z;
            const float d3 = xv[c4 * 4 + 3] - cv.w;
            d += d0 * d0 + d1 * d1 + d2 * d2 + d3 * d3;
        }
        dist[k] = valid ? d : 1e30f;
    }
    float mind = dist[0];
    #pragma unroll
    for (int k = 1; k < 9; ++k) mind = fminf(mind, dist[k]);
    float sum = 0.f;
    #pragma unroll
    for (int k = 0; k < 9; ++k) {
        const float e = (dist[k] < 1e29f) ? __expf(mind - dist[k]) : 0.f;
        aff[k] = e;
        sum += e;
    }
    const float inv = 1.f / sum;   // home superpixel always valid
    #pragma unroll
    for (int k = 0; k < 9; ++k) aff[k] *= inv;
}

// K1: initial centroids = tile means. No zero strip (measured worse, R5).
__global__ __launch_bounds__(256) void k_cent0(const float* __restrict__ x,
                                               float* __restrict__ cent0) {
    const int blk = blockIdx.x;            // b*S_ + s
    const int b = blk >> 8, s = blk & 255;
    const int sy = s >> 4, sx = s & 15;
    const int t = threadIdx.x;
    const int w = t >> 6, lane = t & 63;
    const float* base = x + (size_t)b * C_ * N_ + (sy * 16) * W_ + sx * 16;
    #pragma unroll
    for (int i = 0; i < 8; ++i) {
        const int c = i * 4 + w;
        const float4 v = *(const float4*)(base + (size_t)c * N_ + (lane >> 2) * W_ + (lane & 3) * 4);
        const float sm = wave_sum(v.x + v.y + v.z + v.w);
        if (lane == 0) cent0[(size_t)blk * C_ + c] = sm * (1.0f / 256.0f);
    }
}

// Zero strip rows [r0,r1) of this block's output plane (f4-rows of 256).
// EXCL: skip this block's 3x3 tile neighborhood (k_aff9 only).
template <bool EXCL>
__device__ __forceinline__ void zero_strip(float* plane, int t, int r0, int r1,
                                           int sy, int sx) {
    for (int i = r0; i < r1; ++i) {
        const int q = i * 256 + t;
        if (EXCL) {
            const int ty = q >> 10, tx = (q >> 2) & 15;
            if (((unsigned)(ty - sy + 1) <= 2u) & ((unsigned)(tx - sx + 1) <= 2u))
                continue;
        }
        nt_zero4(plane + q * 4);
    }
}

// K2: iteration 0 partials + zero strip rows [0,40) (unconditional).
// Even blocks: strip pre-barrier-1. Odd blocks: after last barrier.
__global__ __launch_bounds__(256) void k_part(const float* __restrict__ x,
                                              const float* __restrict__ cent0,
                                              float* __restrict__ part,
                                              float* __restrict__ out) {
    const int blk = blockIdx.x;
    const int b = blk >> 8, s = blk & 255;
    const int sy = s >> 4, sx = s & 15;
    const int t = threadIdx.x;
    const int w = t >> 6, lane = t & 63;
    const bool early = (blk & 1) == 0;
    float* plane = out + ((size_t)blk << 16);
    __shared__ float cl[9][C_];
    __shared__ float xsh[C_][PADP];
    __shared__ float affs[9][PADP];
    __shared__ float lden[4][9];
    {   // cl fill: k=0..7 by all, k=8 by t<32
        const int k = t >> 5, c = t & 31;
        const int ny = sy + k / 3 - 1, nx = sx + k % 3 - 1;
        const bool valid = (ny >= 0) & (ny < NH_) & (nx >= 0) & (nx < NH_);
        cl[k][c] = valid ? cent0[(size_t)(b * S_ + ny * NH_ + nx) * C_ + c] : 0.f;
    }
    if (t < 32) {
        const int ny = sy + 1, nx = sx + 1;
        const bool valid = (ny < NH_) & (nx < NH_);
        cl[8][t] = valid ? cent0[(size_t)(b * S_ + ny * NH_ + nx) * C_ + t] : 0.f;
    }
    stage_tile(x, b, sy, sx, t, xsh);
    if (early) zero_strip<false>(plane, t, 0, 40, sy, sx);
    __syncthreads();
    float xv[C_];
    #pragma unroll
    for (int c = 0; c < C_; ++c) xv[c] = xsh[c][t];   // conflict-free
    float aff[9];
    compute_aff(xv, cl, sy, sx, aff);
    #pragma unroll
    for (int k = 0; k < 9; ++k) {
        affs[k][t] = aff[k];
        const float v = wave_sum(aff[k]);
        if (lane == 0) lden[w][k] = v;
    }
    __syncthreads();                       // LAST barrier
    if (!early) zero_strip<false>(plane, t, 0, 40, sy, sx);
    {   // Phase B: outputs t = k*32+c for k=0..7; t<32 also k=8.
        const int k = t >> 5, c = t & 31;
        float acc = 0.f;
        #pragma unroll 4
        for (int p = 0; p < 256; p += 4) {
            const float4 a = *(const float4*)&affs[k][p];
            const float4 xc = *(const float4*)&xsh[c][p];
            acc += a.x * xc.x + a.y * xc.y + a.z * xc.z + a.w * xc.w;
        }
        part[(size_t)blk * PSTR + t] = acc;
    }
    if (t < 32) {
        float acc = 0.f;
        #pragma unroll 4
        for (int p = 0; p < 256; p += 4) {
            const float4 a = *(const float4*)&affs[8][p];
            const float4 xc = *(const float4*)&xsh[t][p];
            acc += a.x * xc.x + a.y * xc.y + a.z * xc.z + a.w * xc.w;
        }
        part[(size_t)blk * PSTR + 256 + t] = acc;
    }
    if (t < 9)
        part[(size_t)blk * PSTR + 288 + t] =
            lden[0][t] + lden[1][t] + lden[2][t] + lden[3][t];
}

// cent1[b,(ny,nx),c] = num/(den+1e-16), gathered from 9 source blocks'
// partials (part is L2-hot, 1.2 MB).
__device__ __forceinline__ float gather_cent1(const float* __restrict__ part,
                                              int b, int ny, int nx, int c) {
    float num = 0.f, den = 0.f;
    #pragma unroll
    for (int k2 = 0; k2 < 9; ++k2) {
        const int syp = ny - (k2 / 3 - 1), sxp = nx - (k2 % 3 - 1);
        if ((syp >= 0) & (syp < NH_) & (sxp >= 0) & (sxp < NH_)) {
            const size_t base = (size_t)(b * S_ + syp * NH_ + sxp) * PSTR;
            num += part[base + k2 * 32 + c];
            den += part[base + 288 + k2];
        }
    }
    return num / (den + 1e-16f);
}

// K3: iteration-1 affinities vs cent1 (gathered in-kernel) + zero strip rows
// [40,64) (3x3-excluded, same parity stagger) + direct value scatter.
__global__ __launch_bounds__(256) void k_aff9(const float* __restrict__ x,
                                              const float* __restrict__ part,
                                              float* __restrict__ out) {
    const int blk = blockIdx.x;
    const int b = blk >> 8, s = blk & 255;
    const int sy = s >> 4, sx = s & 15;
    const int t = threadIdx.x;
    const bool early = (blk & 1) == 0;
    float* plane = out + ((size_t)blk << 16);
    __shared__ float cl[9][C_];
    __shared__ float xsh[C_][PADP];
    __shared__ float affs[9][PADP];
    {   // cl = cent1 of the 9 neighbors, computed on the fly
        const int k = t >> 5, c = t & 31;
        const int ny = sy + k / 3 - 1, nx = sx + k % 3 - 1;
        const bool valid = (ny >= 0) & (ny < NH_) & (nx >= 0) & (nx < NH_);
        cl[k][c] = valid ? gather_cent1(part, b, ny, nx, c) : 0.f;
    }
    if (t < 32) {
        const int ny = sy + 1, nx = sx + 1;
        const bool valid = (ny < NH_) & (nx < NH_);
        cl[8][t] = valid ? gather_cent1(part, b, ny, nx, t) : 0.f;
    }
    stage_tile(x, b, sy, sx, t, xsh);
    if (early) zero_strip<true>(plane, t, 40, 64, sy, sx);
    __syncthreads();
    float xv[C_];
    #pragma unroll
    for (int c = 0; c < C_; ++c) xv[c] = xsh[c][t];
    float aff[9];
    compute_aff(xv, cl, sy, sx, aff);
    #pragma unroll
    for (int k = 0; k < 9; ++k) affs[k][t] = aff[k];
    __syncthreads();                       // LAST barrier
    if (!early) zero_strip<true>(plane, t, 40, 64, sy, sx);
    // Scatter: for valid neighbor k, write this tile's 16x16 values into
    // plane s'=(ny,nx) — 576 float4 total (64B row-segments), nontemporal.
    #pragma unroll
    for (int i = 0; i < 3; ++i) {
        const int idx = i * 256 + t;
        if (idx < 576) {
            const int k = idx >> 6, j4 = idx & 63;
            const int ny = sy + k / 3 - 1, nx = sx + k % 3 - 1;
            if ((ny >= 0) & (ny < NH_) & (nx >= 0) & (nx < NH_)) {
                const int gq = (sy * 16 + (j4 >> 2)) * 64 + sx * 4 + (j4 & 3);
                float* dst = out + (((size_t)(b * S_ + ny * NH_ + nx) << 16) + gq * 4);
                nt_store4(dst, affs[k][j4 * 4], affs[k][j4 * 4 + 1],
                               affs[k][j4 * 4 + 2], affs[k][j4 * 4 + 3]);
            }
        }
    }
    if ((blk | t) == 0) out[(size_t)B_ * S_ * N_] = 256.0f;  // output 1: S
}

extern "C" void kernel_launch(void* const* d_in, const int* in_sizes, int n_in,
                              void* d_out, int out_size, void* d_ws, size_t ws_size,
                              hipStream_t stream) {
    const float* x = (const float*)d_in[0];
    float* ws = (float*)d_ws;
    // ws layout (floats): cent0[32768] | part[1024*304]
    float* cent0 = ws;
    float* part  = ws + 32768;
    float* out   = (float*)d_out;

    hipLaunchKernelGGL(k_cent0, dim3(B_ * S_), dim3(256), 0, stream, x, cent0);
    hipLaunchKernelGGL(k_part,  dim3(B_ * S_), dim3(256), 0, stream, x, cent0, part, out);
    hipLaunchKernelGGL(k_aff9,  dim3(B_ * S_), dim3(256), 0, stream, x, part, out);
}

// Round 8
// 314.000 us; speedup vs baseline: 1.0595x; 1.0108x over previous
//
#include <hip/hip_runtime.h>
#include <hip/hip_fp16.h>

// SSN soft-superpixel assignment. Fixed shapes: x (4,32,256,256) fp32, s=16.
// M = 0 -> grid channels are identically zero; drop them (C=32).
//
// 3-kernel pipeline; 254 MB of output zeros fused into k_part/k_aff9 as NT
// stores with parity stagger. KEY SIZING: LDS < 40 KB (affs in fp16) so 4
// blocks/CU are resident -> the 1024-block grid runs in ONE round (256 CU x 4)
// with no low-occupancy straggler round (44 KB/3-per-CU left a 256-block tail).
#define B_  4
#define C_  32
#define W_  256
#define N_  65536   // H*W
#define NH_ 16      // 16x16 superpixel grid
#define S_  256
#define PADP 260    // xsh row stride (floats): 1040 B = 16B-mult, 4-way b128 conflict only
#define PADH 260    // affs row stride (halves): 520 B, 8B-mult for half4 reads
#define PSTR 304    // per-block partial stride: 288 num + 9 den + pad

typedef float vf4 __attribute__((ext_vector_type(4)));
typedef _Float16 h4 __attribute__((ext_vector_type(4)));

__device__ __forceinline__ float wave_sum(float v) {
    v += __shfl_down(v, 32);
    v += __shfl_down(v, 16);
    v += __shfl_down(v, 8);
    v += __shfl_down(v, 4);
    v += __shfl_down(v, 2);
    v += __shfl_down(v, 1);
    return v;  // lane 0 holds the 64-lane sum
}

__device__ __forceinline__ void nt_store4(float* p, float a, float b, float c, float d) {
    vf4 v = {a, b, c, d};
    __builtin_nontemporal_store(v, (vf4*)p);
}
__device__ __forceinline__ void nt_zero4(float* p) { nt_store4(p, 0.f, 0.f, 0.f, 0.f); }

// Stage this block's 16x16x32 tile of x into xsh[c][p] (p = py*16+px),
// coalesced float4: idx -> channel c = idx>>6, f4 p4 = idx&63.
__device__ __forceinline__ void stage_tile(const float* __restrict__ x,
                                           int b, int sy, int sx, int t,
                                           float (*xsh)[PADP]) {
    const float* base = x + (size_t)b * C_ * N_ + (sy * 16) * W_ + sx * 16;
    #pragma unroll
    for (int i = 0; i < 8; ++i) {
        const int idx = i * 256 + t;
        const int c = idx >> 6, p4 = idx & 63;
        const float4 v = *(const float4*)(base + (size_t)c * N_ + (p4 >> 2) * W_ + (p4 & 3) * 4);
        *(float4*)&xsh[c][p4 * 4] = v;
    }
}

// Per-pixel softmax over the 3x3 superpixel neighborhood (cl[k] zeroed for
// invalid k; masked to aff=0 anyway). Equivalent to ref softmax(-dist)+mask.
__device__ __forceinline__ void compute_aff(const float xv[C_], const float (*cl)[C_],
                                            int sy, int sx, float aff[9]) {
    float dist[9];
    #pragma unroll
    for (int k = 0; k < 9; ++k) {
        const int ny = sy + k / 3 - 1, nx = sx + k % 3 - 1;
        const bool valid = (ny >= 0) & (ny < NH_) & (nx >= 0) & (nx < NH_);
        float d = 0.f;
        #pragma unroll
        for (int c4 = 0; c4 < C_ / 4; ++c4) {
            const float4 cv = *(const float4*)&cl[k][c4 * 4];   // LDS broadcast
            const float d0 = xv[c4 * 4 + 0] - cv.x;
            const float d1 = xv[c4 * 4 + 1] - cv.y;
            const float d2 = xv[c4 * 4 + 2] - cv.z;
            const float d3 = xv[c4 * 4 + 3] - cv.w;
            d += d0 * d0 + d1 * d1 + d2 * d2 + d3 * d3;
        }
        dist[k] = valid ? d : 1e30f;
    }
    float mind = dist[0];
    #pragma unroll
    for (int k = 1; k < 9; ++k) mind = fminf(mind, dist[k]);
    float sum = 0.f;
    #pragma unroll
    for (int k = 0; k < 9; ++k) {
        const float e = (dist[k] < 1e29f) ? __expf(mind - dist[k]) : 0.f;
        aff[k] = e;
        sum += e;
    }
    const float inv = 1.f / sum;   // home superpixel always valid
    #pragma unroll
    for (int k = 0; k < 9; ++k) aff[k] *= inv;
}

// K1: initial centroids = tile means.
__global__ __launch_bounds__(256) void k_cent0(const float* __restrict__ x,
                                               float* __restrict__ cent0) {
    const int blk = blockIdx.x;            // b*S_ + s
    const int b = blk >> 8, s = blk & 255;
    const int sy = s >> 4, sx = s & 15;
    const int t = threadIdx.x;
    const int w = t >> 6, lane = t & 63;
    const float* base = x + (size_t)b * C_ * N_ + (sy * 16) * W_ + sx * 16;
    #pragma unroll
    for (int i = 0; i < 8; ++i) {
        const int c = i * 4 + w;
        const float4 v = *(const float4*)(base + (size_t)c * N_ + (lane >> 2) * W_ + (lane & 3) * 4);
        const float sm = wave_sum(v.x + v.y + v.z + v.w);
        if (lane == 0) cent0[(size_t)blk * C_ + c] = sm * (1.0f / 256.0f);
    }
}

// Zero strip rows [r0,r1) of this block's output plane (f4-rows of 256).
// EXCL: skip this block's 3x3 tile neighborhood (k_aff9 only).
template <bool EXCL>
__device__ __forceinline__ void zero_strip(float* plane, int t, int r0, int r1,
                                           int sy, int sx) {
    #pragma unroll 4
    for (int i = r0; i < r1; ++i) {
        const int q = i * 256 + t;
        if (EXCL) {
            const int ty = q >> 10, tx = (q >> 2) & 15;
            if (((unsigned)(ty - sy + 1) <= 2u) & ((unsigned)(tx - sx + 1) <= 2u))
                continue;
        }
        nt_zero4(plane + q * 4);
    }
}

// K2: iteration 0 partials + zero strip rows [0,36) (unconditional).
// Even blocks: strip pre-barrier-1. Odd blocks: after last barrier.
__global__ __launch_bounds__(256, 4) void k_part(const float* __restrict__ x,
                                                 const float* __restrict__ cent0,
                                                 float* __restrict__ part,
                                                 float* __restrict__ out) {
    const int blk = blockIdx.x;
    const int b = blk >> 8, s = blk & 255;
    const int sy = s >> 4, sx = s & 15;
    const int t = threadIdx.x;
    const int w = t >> 6, lane = t & 63;
    const bool early = (blk & 1) == 0;
    float* plane = out + ((size_t)blk << 16);
    __shared__ float cl[9][C_];
    __shared__ float xsh[C_][PADP];
    __shared__ _Float16 affs[9][PADH];     // fp16: keeps LDS < 40 KB (4 blk/CU)
    __shared__ float lden[4][9];
    {   // cl fill: k=0..7 by all, k=8 by t<32
        const int k = t >> 5, c = t & 31;
        const int ny = sy + k / 3 - 1, nx = sx + k % 3 - 1;
        const bool valid = (ny >= 0) & (ny < NH_) & (nx >= 0) & (nx < NH_);
        cl[k][c] = valid ? cent0[(size_t)(b * S_ + ny * NH_ + nx) * C_ + c] : 0.f;
    }
    if (t < 32) {
        const int ny = sy + 1, nx = sx + 1;
        const bool valid = (ny < NH_) & (nx < NH_);
        cl[8][t] = valid ? cent0[(size_t)(b * S_ + ny * NH_ + nx) * C_ + t] : 0.f;
    }
    stage_tile(x, b, sy, sx, t, xsh);
    if (early) zero_strip<false>(plane, t, 0, 36, sy, sx);
    __syncthreads();
    float xv[C_];
    #pragma unroll
    for (int c = 0; c < C_; ++c) xv[c] = xsh[c][t];   // conflict-free
    float aff[9];
    compute_aff(xv, cl, sy, sx, aff);
    #pragma unroll
    for (int k = 0; k < 9; ++k) {
        affs[k][t] = (_Float16)aff[k];
        const float v = wave_sum(aff[k]);
        if (lane == 0) lden[w][k] = v;
    }
    __syncthreads();                       // LAST barrier
    if (!early) zero_strip<false>(plane, t, 0, 36, sy, sx);
    {   // Phase B: outputs t = k*32+c for k=0..7; t<32 also k=8.
        const int k = t >> 5, c = t & 31;
        float acc = 0.f;
        #pragma unroll 4
        for (int p = 0; p < 256; p += 4) {
            const h4 a = *(const h4*)&affs[k][p];
            const float4 xc = *(const float4*)&xsh[c][p];
            acc += (float)a.x * xc.x + (float)a.y * xc.y +
                   (float)a.z * xc.z + (float)a.w * xc.w;
        }
        part[(size_t)blk * PSTR + t] = acc;
    }
    if (t < 32) {
        float acc = 0.f;
        #pragma unroll 4
        for (int p = 0; p < 256; p += 4) {
            const h4 a = *(const h4*)&affs[8][p];
            const float4 xc = *(const float4*)&xsh[t][p];
            acc += (float)a.x * xc.x + (float)a.y * xc.y +
                   (float)a.z * xc.z + (float)a.w * xc.w;
        }
        part[(size_t)blk * PSTR + 256 + t] = acc;
    }
    if (t < 9)
        part[(size_t)blk * PSTR + 288 + t] =
            lden[0][t] + lden[1][t] + lden[2][t] + lden[3][t];
}

// cent1[b,(ny,nx),c] = num/(den+1e-16), gathered from 9 source blocks'
// partials (part is L2-hot, 1.2 MB).
__device__ __forceinline__ float gather_cent1(const float* __restrict__ part,
                                              int b, int ny, int nx, int c) {
    float num = 0.f, den = 0.f;
    #pragma unroll
    for (int k2 = 0; k2 < 9; ++k2) {
        const int syp = ny - (k2 / 3 - 1), sxp = nx - (k2 % 3 - 1);
        if ((syp >= 0) & (syp < NH_) & (sxp >= 0) & (sxp < NH_)) {
            const size_t base = (size_t)(b * S_ + syp * NH_ + sxp) * PSTR;
            num += part[base + k2 * 32 + c];
            den += part[base + 288 + k2];
        }
    }
    return num / (den + 1e-16f);
}

// K3: iteration-1 affinities vs cent1 (gathered in-kernel) + zero strip rows
// [36,64) (3x3-excluded, parity stagger) + direct value scatter from LDS.
__global__ __launch_bounds__(256, 4) void k_aff9(const float* __restrict__ x,
                                                 const float* __restrict__ part,
                                                 float* __restrict__ out) {
    const int blk = blockIdx.x;
    const int b = blk >> 8, s = blk & 255;
    const int sy = s >> 4, sx = s & 15;
    const int t = threadIdx.x;
    const bool early = (blk & 1) == 0;
    float* plane = out + ((size_t)blk << 16);
    __shared__ float cl[9][C_];
    __shared__ float xsh[C_][PADP];
    __shared__ _Float16 affs[9][PADH];
    {   // cl = cent1 of the 9 neighbors, computed on the fly
        const int k = t >> 5, c = t & 31;
        const int ny = sy + k / 3 - 1, nx = sx + k % 3 - 1;
        const bool valid = (ny >= 0) & (ny < NH_) & (nx >= 0) & (nx < NH_);
        cl[k][c] = valid ? gather_cent1(part, b, ny, nx, c) : 0.f;
    }
    if (t < 32) {
        const int ny = sy + 1, nx = sx + 1;
        const bool valid = (ny < NH_) & (nx < NH_);
        cl[8][t] = valid ? gather_cent1(part, b, ny, nx, t) : 0.f;
    }
    stage_tile(x, b, sy, sx, t, xsh);
    if (early) zero_strip<true>(plane, t, 36, 64, sy, sx);
    __syncthreads();
    float xv[C_];
    #pragma unroll
    for (int c = 0; c < C_; ++c) xv[c] = xsh[c][t];
    float aff[9];
    compute_aff(xv, cl, sy, sx, aff);
    #pragma unroll
    for (int k = 0; k < 9; ++k) affs[k][t] = (_Float16)aff[k];
    __syncthreads();                       // LAST barrier
    if (!early) zero_strip<true>(plane, t, 36, 64, sy, sx);
    // Scatter: for valid neighbor k, write this tile's 16x16 values into
    // plane s'=(ny,nx) — 576 float4 total (64B row-segments), nontemporal.
    #pragma unroll
    for (int i = 0; i < 3; ++i) {
        const int idx = i * 256 + t;
        if (idx < 576) {
            const int k = idx >> 6, j4 = idx & 63;
            const int ny = sy + k / 3 - 1, nx = sx + k % 3 - 1;
            if ((ny >= 0) & (ny < NH_) & (nx >= 0) & (nx < NH_)) {
                const h4 a = *(const h4*)&affs[k][j4 * 4];
                const int gq = (sy * 16 + (j4 >> 2)) * 64 + sx * 4 + (j4 & 3);
                float* dst = out + (((size_t)(b * S_ + ny * NH_ + nx) << 16) + gq * 4);
                nt_store4(dst, (float)a.x, (float)a.y, (float)a.z, (float)a.w);
            }
        }
    }
    if ((blk | t) == 0) out[(size_t)B_ * S_ * N_] = 256.0f;  // output 1: S
}

extern "C" void kernel_launch(void* const* d_in, const int* in_sizes, int n_in,
                              void* d_out, int out_size, void* d_ws, size_t ws_size,
                              hipStream_t stream) {
    const float* x = (const float*)d_in[0];
    float* ws = (float*)d_ws;
    // ws layout (floats): cent0[32768] | part[1024*304]
    float* cent0 = ws;
    float* part  = ws + 32768;
    float* out   = (float*)d_out;

    hipLaunchKernelGGL(k_cent0, dim3(B_ * S_), dim3(256), 0, stream, x, cent0);
    hipLaunchKernelGGL(k_part,  dim3(B_ * S_), dim3(256), 0, stream, x, cent0, part, out);
    hipLaunchKernelGGL(k_aff9,  dim3(B_ * S_), dim3(256), 0, stream, x, part, out);
}